// Round 2
// baseline (427.738 us; speedup 1.0000x reference)
//
#include <hip/hip_runtime.h>

// MoEALU add + xor over one-hot byte-distribution encodings.
//
// Inputs are exact one-hot [B,4,256] float32 encodings; with SCALE=100 every
// softmax in the reference returns a distribution whose peak is exactly 1.0f
// in float32 (off-peak entries are exp(-100) ~ 3.8e-44, below bf16/f32
// comparison noise). The soft-ALU collapses to exact integer add/xor with
// exact one-hot outputs.
//
// Layout: one batch element per WAVE (64 lanes). Lane l loads float4 index
// k*64+l of the element's 256 float4s; k = byte row. Hot index recovered via
// one __ballot + one __shfl per row — no LDS, no __syncthreads, waves fully
// independent. Traffic: 268 MB read + 268 MB write => ~84 us floor @6.4 TB/s.

__global__ __launch_bounds__(256) void moe_alu_kernel(
    const float* __restrict__ A,
    const float* __restrict__ Bmat,
    float* __restrict__ out,
    int B)
{
    const int wid  = blockIdx.x * 4 + (threadIdx.x >> 6);  // batch element
    const int lane = threadIdx.x & 63;
    if (wid >= B) return;

    const float4* a4 = reinterpret_cast<const float4*>(A)    + (size_t)wid * 256;
    const float4* b4 = reinterpret_cast<const float4*>(Bmat) + (size_t)wid * 256;

    // Load all 8 float4s up front (no barriers -> compiler keeps them in flight).
    float4 av[4], bv[4];
    #pragma unroll
    for (int k = 0; k < 4; ++k) {
        av[k] = a4[k * 64 + lane];
        bv[k] = b4[k * 64 + lane];
    }

    unsigned a32 = 0, b32 = 0;
    #pragma unroll
    for (int k = 0; k < 4; ++k) {
        // Local candidate index within this byte row (floats 4*lane..4*lane+3).
        int ai = 0, bi = 0;
        if (av[k].x > 0.5f) ai = 4 * lane + 0;
        if (av[k].y > 0.5f) ai = 4 * lane + 1;
        if (av[k].z > 0.5f) ai = 4 * lane + 2;
        if (av[k].w > 0.5f) ai = 4 * lane + 3;
        if (bv[k].x > 0.5f) bi = 4 * lane + 0;
        if (bv[k].y > 0.5f) bi = 4 * lane + 1;
        if (bv[k].z > 0.5f) bi = 4 * lane + 2;
        if (bv[k].w > 0.5f) bi = 4 * lane + 3;

        const bool ha = (av[k].x > 0.5f) | (av[k].y > 0.5f) |
                        (av[k].z > 0.5f) | (av[k].w > 0.5f);
        const bool hb = (bv[k].x > 0.5f) | (bv[k].y > 0.5f) |
                        (bv[k].z > 0.5f) | (bv[k].w > 0.5f);
        const unsigned long long ma = __ballot(ha);
        const unsigned long long mb = __ballot(hb);
        const int sa = ma ? (__ffsll((unsigned long long)ma) - 1) : 0;
        const int sb = mb ? (__ffsll((unsigned long long)mb) - 1) : 0;

        const unsigned abyte = (unsigned)__shfl(ai, sa, 64);  // broadcast
        const unsigned bbyte = (unsigned)__shfl(bi, sb, 64);
        a32 |= abyte << (8 * k);
        b32 |= bbyte << (8 * k);
    }

    const unsigned s32 = a32 + b32;   // exact 32-bit carry chain
    const unsigned x32 = a32 ^ b32;

    float4* oadd = reinterpret_cast<float4*>(out) + (size_t)wid * 256;
    float4* oxor = reinterpret_cast<float4*>(out) + ((size_t)B + (size_t)wid) * 256;

    #pragma unroll
    for (int k = 0; k < 4; ++k) {
        const unsigned sbyte = (s32 >> (8 * k)) & 255u;
        const unsigned xbyte = (x32 >> (8 * k)) & 255u;
        const unsigned pos   = 4u * (unsigned)lane;

        float4 va, vx;
        va.x = (sbyte == pos + 0u) ? 1.0f : 0.0f;
        va.y = (sbyte == pos + 1u) ? 1.0f : 0.0f;
        va.z = (sbyte == pos + 2u) ? 1.0f : 0.0f;
        va.w = (sbyte == pos + 3u) ? 1.0f : 0.0f;
        vx.x = (xbyte == pos + 0u) ? 1.0f : 0.0f;
        vx.y = (xbyte == pos + 1u) ? 1.0f : 0.0f;
        vx.z = (xbyte == pos + 2u) ? 1.0f : 0.0f;
        vx.w = (xbyte == pos + 3u) ? 1.0f : 0.0f;

        oadd[k * 64 + lane] = va;
        oxor[k * 64 + lane] = vx;
    }
}

extern "C" void kernel_launch(void* const* d_in, const int* in_sizes, int n_in,
                              void* d_out, int out_size, void* d_ws, size_t ws_size,
                              hipStream_t stream) {
    const float* a = (const float*)d_in[0];
    const float* b = (const float*)d_in[1];
    float* out = (float*)d_out;
    const int B = in_sizes[0] / 1024;   // [B,4,256]

    const int blocks = (B + 3) / 4;     // one wave (64 lanes) per batch element
    moe_alu_kernel<<<blocks, 256, 0, stream>>>(a, b, out, B);
}

// Round 4
// 413.466 us; speedup vs baseline: 1.0345x; 1.0345x over previous
//
#include <hip/hip_runtime.h>

// MoEALU add + xor over one-hot byte-distribution encodings.
//
// Inputs are exact one-hot [B,4,256] float32 encodings; with SCALE=100 every
// softmax in the reference returns a distribution whose peak is exactly 1.0f
// in float32 (off-peak entries are exp(-100) ~ 3.8e-44). The soft-ALU
// collapses to exact integer add/xor with exact one-hot outputs.
//
// One batch element per WAVE; lane l loads float4 k*64+l (k = byte row).
// Hot index via one __ballot + one __shfl per row — no LDS, no barriers.
// Nontemporal loads/stores (stream-once, bypass L2 allocate) via native
// clang vector type (HIP_vector_type structs are rejected by the builtin).
// Traffic floor: 268 MB read + 268 MB write ~ 85 us.

typedef float vfloat4 __attribute__((ext_vector_type(4)));

__global__ __launch_bounds__(256) void moe_alu_kernel(
    const float* __restrict__ A,
    const float* __restrict__ Bmat,
    float* __restrict__ out,
    int B)
{
    const int wid  = blockIdx.x * 4 + (threadIdx.x >> 6);  // batch element
    const int lane = threadIdx.x & 63;
    if (wid >= B) return;

    const vfloat4* a4 = reinterpret_cast<const vfloat4*>(A)    + (size_t)wid * 256;
    const vfloat4* b4 = reinterpret_cast<const vfloat4*>(Bmat) + (size_t)wid * 256;

    // Load all 8 float4s up front, nontemporal (stream-once).
    vfloat4 av[4], bv[4];
    #pragma unroll
    for (int k = 0; k < 4; ++k) {
        av[k] = __builtin_nontemporal_load(&a4[k * 64 + lane]);
        bv[k] = __builtin_nontemporal_load(&b4[k * 64 + lane]);
    }

    unsigned a32 = 0, b32 = 0;
    #pragma unroll
    for (int k = 0; k < 4; ++k) {
        int ai = 0, bi = 0;
        if (av[k].x > 0.5f) ai = 4 * lane + 0;
        if (av[k].y > 0.5f) ai = 4 * lane + 1;
        if (av[k].z > 0.5f) ai = 4 * lane + 2;
        if (av[k].w > 0.5f) ai = 4 * lane + 3;
        if (bv[k].x > 0.5f) bi = 4 * lane + 0;
        if (bv[k].y > 0.5f) bi = 4 * lane + 1;
        if (bv[k].z > 0.5f) bi = 4 * lane + 2;
        if (bv[k].w > 0.5f) bi = 4 * lane + 3;

        const bool ha = (av[k].x > 0.5f) | (av[k].y > 0.5f) |
                        (av[k].z > 0.5f) | (av[k].w > 0.5f);
        const bool hb = (bv[k].x > 0.5f) | (bv[k].y > 0.5f) |
                        (bv[k].z > 0.5f) | (bv[k].w > 0.5f);
        const unsigned long long ma = __ballot(ha);
        const unsigned long long mb = __ballot(hb);
        const int sa = ma ? (__ffsll(ma) - 1) : 0;
        const int sb = mb ? (__ffsll(mb) - 1) : 0;

        const unsigned abyte = (unsigned)__shfl(ai, sa, 64);  // broadcast
        const unsigned bbyte = (unsigned)__shfl(bi, sb, 64);
        a32 |= abyte << (8 * k);
        b32 |= bbyte << (8 * k);
    }

    const unsigned s32 = a32 + b32;   // exact 32-bit carry chain
    const unsigned x32 = a32 ^ b32;

    vfloat4* oadd = reinterpret_cast<vfloat4*>(out) + (size_t)wid * 256;
    vfloat4* oxor = reinterpret_cast<vfloat4*>(out) + ((size_t)B + (size_t)wid) * 256;

    #pragma unroll
    for (int k = 0; k < 4; ++k) {
        const unsigned sbyte = (s32 >> (8 * k)) & 255u;
        const unsigned xbyte = (x32 >> (8 * k)) & 255u;
        const unsigned pos   = 4u * (unsigned)lane;

        vfloat4 va, vx;
        va.x = (sbyte == pos + 0u) ? 1.0f : 0.0f;
        va.y = (sbyte == pos + 1u) ? 1.0f : 0.0f;
        va.z = (sbyte == pos + 2u) ? 1.0f : 0.0f;
        va.w = (sbyte == pos + 3u) ? 1.0f : 0.0f;
        vx.x = (xbyte == pos + 0u) ? 1.0f : 0.0f;
        vx.y = (xbyte == pos + 1u) ? 1.0f : 0.0f;
        vx.z = (xbyte == pos + 2u) ? 1.0f : 0.0f;
        vx.w = (xbyte == pos + 3u) ? 1.0f : 0.0f;

        __builtin_nontemporal_store(va, &oadd[k * 64 + lane]);
        __builtin_nontemporal_store(vx, &oxor[k * 64 + lane]);
    }
}

extern "C" void kernel_launch(void* const* d_in, const int* in_sizes, int n_in,
                              void* d_out, int out_size, void* d_ws, size_t ws_size,
                              hipStream_t stream) {
    const float* a = (const float*)d_in[0];
    const float* b = (const float*)d_in[1];
    float* out = (float*)d_out;
    const int B = in_sizes[0] / 1024;   // [B,4,256]

    const int blocks = (B + 3) / 4;     // one wave (64 lanes) per batch element
    moe_alu_kernel<<<blocks, 256, 0, stream>>>(a, b, out, B);
}